// Round 13
// baseline (150.105 us; speedup 1.0000x reference)
//
#include <hip/hip_runtime.h>

// KANConv2D: out[b,h,w,f] = conv3x3(x,K)[.,f] + exp(-gamma * d[.,f]) + bias[f]
// d = ||patch||^2 + ||c_f||^2 - 2*patch.c_f ; gamma = (N*F)/(2*sum(d))
//
// v20 (from v13 best=142.5; v19 fully reverted):
//  - Register accounting: gfx950 unified VGPR/AGPR file -> real footprint =
//    VGPR_Count(60) + acc AGPRs(64) = 124 -> 4 waves/SIMD (matches Occ 32%;
//    v7's 220 -> 2 waves, Occ 17%). Occupancy is ACC-register-bound.
//  - NEW: drop the depth-1 B prefetch registers (16 VGPRs) -> B fragments
//    loaded inside each slab body (L2-hot; latency covered ACROSS waves
//    instead of within one), and pin __launch_bounds__(512,5) -> 102-reg
//    budget -> 5 waves/SIMD (+25% latency cover). ~6-reg squeeze left to
//    the allocator (v12's failure was a 22-reg overshoot; this is not that).
//  - Everything else verbatim v13: k_prep/k_gamma(512 blocks), fused-sqnorm
//    staging, barrier-free K-loop, post-loop per-wave gamma reduce.

#define B_ 32
#define H_ 64
#define W_ 64
#define C_ 64
#define F_ 128
#define P_ 576
#define NPIX (B_*H_*W_)          // 131072
#define NF   (NPIX*F_)           // 16777216

typedef __bf16  bf16x8 __attribute__((ext_vector_type(8)));
typedef float   f32x4  __attribute__((ext_vector_type(4)));

union BFU { __bf16 h; ushort s; };
union PKU { __bf16 h[2]; uint u; };

__device__ __forceinline__ ushort f2bf(float f) { BFU q; q.h = (__bf16)f; return q.s; }
__device__ __forceinline__ uint pk(float a, float b) {
    PKU q; q.h[0] = (__bf16)a; q.h[1] = (__bf16)b; return q.u;
}

// ---------------- P: wsB slab pack | cn,Scn | chat tab ----------
// slab s = kc*2+ks (18 slabs x 8192 ushorts). within slab:
//   off = mat*4096 + ntg*512 + (quad*16+l16)*8 + j
//   where p = kc*64 + ks*32 + quad*8 + j, f = ntg*16 + l16.
__global__ void k_prep(const float* __restrict__ wgt, const float* __restrict__ ctrl,
                       ushort* __restrict__ wsB, float* __restrict__ cn,
                       float* __restrict__ accum, float* __restrict__ tab) {
    __shared__ __attribute__((aligned(16))) float sh[1024];
    const int t = threadIdx.x;

    if (blockIdx.x < 288) {
        int e = blockIdx.x * 256 + t;             // < 73728
        int p = e >> 7, f = e & 127;
        int kc = p >> 6, r = p & 63;
        int ks = r >> 5, quad = (r >> 3) & 3, j = r & 7;
        int ntg = f >> 4, l16 = f & 15;
        int off0 = (kc * 2 + ks) * 8192 + ntg * 512 + (quad * 16 + l16) * 8 + j;
        wsB[off0]        = f2bf(wgt[e]);    // mat 0 (kernel)
        wsB[off0 + 4096] = f2bf(ctrl[e]);   // mat 1 (control)
        return;
    }
    if (blockIdx.x == 288) {
        // cn[f] + Scn. thread = (pc 0..7, col 0..31).
        int col = t & 31, pc8 = t >> 5;
        f32x4 a = {0.f, 0.f, 0.f, 0.f};
        const float* base = ctrl + col * 4;
        #pragma unroll 4
        for (int p = pc8 * 72; p < pc8 * 72 + 72; ++p) {
            f32x4 v = *(const f32x4*)(base + p * F_);
            a += v * v;
        }
        f32x4* sh4 = (f32x4*)sh;
        sh4[t] = a;
        __syncthreads();
        f32x4 s = {0.f, 0.f, 0.f, 0.f};
        if (t < 32) {
            #pragma unroll
            for (int q = 0; q < 8; ++q) s += sh4[q * 32 + t];
            *(f32x4*)(cn + t * 4) = s;
        }
        float tot = s.x + s.y + s.z + s.w;   // 0 for t>=32
        if (t < 64) {
            #pragma unroll
            for (int off = 32; off >= 1; off >>= 1) tot += __shfl_down(tot, off, 64);
            if (t == 0) accum[0] = tot;      // Scn
        }
        return;
    }

    // block 289: chat[ki][kj][c] = Sum_f ctrl[ki,kj,c,f]; 9 border variants
    for (int e = t; e < 576; e += 256) {
        const f32x4* row = (const f32x4*)(ctrl + e * F_);
        f32x4 a = {0.f, 0.f, 0.f, 0.f};
        #pragma unroll 8
        for (int q = 0; q < 32; ++q) a += row[q];
        sh[e] = a.x + a.y + a.z + a.w;
    }
    __syncthreads();
    for (int idx = t; idx < 576; idx += 256) {
        int q = idx >> 6, c = idx & 63;       // q = ry*3+rx
        int ry = q / 3, rx = q - 3 * ry;
        int my = (ry == 0) ? 3 : (ry == 2) ? 6 : 7;   // valid-ki bitmask
        int mx = (rx == 0) ? 3 : (rx == 2) ? 6 : 7;
        float s = 0.f;
        #pragma unroll
        for (int ki = 0; ki < 3; ++ki)
            #pragma unroll
            for (int kj = 0; kj < 3; ++kj)
                if ((my >> ki & 1) && (mx >> kj & 1))
                    s += sh[(ki * 3 + kj) * 64 + c];
        tab[idx] = s;
    }
}

// ---------------- G: global stats for gamma (one coalesced input pass) ----------
__launch_bounds__(256)
__global__ void k_gamma(const float* __restrict__ in, const float* __restrict__ tab,
                        float* __restrict__ spn, float* __restrict__ spc) {
    __shared__ float shs[4], shp[4];
    const int t = threadIdx.x, seg = t & 15, grp = t >> 4;
    float s = 0.f, pc = 0.f;
    #pragma unroll 4
    for (int it = 0; it < 16; ++it) {
        int pix = blockIdx.x * 256 + it * 16 + grp;
        int y = (pix >> 6) & 63, x = pix & 63;
        float4 v = *((const float4*)(in + pix * 64) + seg);
        int ry = (y == 0) ? 0 : (y == 63) ? 2 : 1;
        int rx = (x == 0) ? 0 : (x == 63) ? 2 : 1;
        float4 tv = *((const float4*)(tab + (ry * 3 + rx) * 64) + seg);
        float wq = (float)((3 - (y == 0) - (y == 63)) * (3 - (x == 0) - (x == 63)));
        s  += wq * (v.x*v.x + v.y*v.y + v.z*v.z + v.w*v.w);
        pc += v.x*tv.x + v.y*tv.y + v.z*tv.z + v.w*tv.w;
    }
    #pragma unroll
    for (int off = 32; off >= 1; off >>= 1) {
        s  += __shfl_down(s,  off, 64);
        pc += __shfl_down(pc, off, 64);
    }
    if ((t & 63) == 0) { shs[t >> 6] = s; shp[t >> 6] = pc; }
    __syncthreads();
    if (t == 0)  spn[blockIdx.x] = shs[0] + shs[1] + shs[2] + shs[3];
    if (t == 64) spc[blockIdx.x] = shp[0] + shp[1] + shp[2] + shp[3];
}

// ---------------- D: fused dual implicit GEMM, B from L2, barrier-free loop ----
// 512 threads = 8 waves: w = mhalf*4 + fq. Each wave: 64M x 32F, BOTH mats.
// LDS: lI [4][68][64] bf16 (XOR-swizzled) | sArr [4][68] f32 | pnAr [128] f32.
// launch_bounds(512,5): 102-reg budget -> 5 waves/SIMD (acc=64 AGPR + <=38).
__launch_bounds__(512, 5)
__global__ void k_main(const float* __restrict__ in, const ushort* __restrict__ wsB,
                       const float* __restrict__ bias, const float* __restrict__ cn,
                       const float* __restrict__ accum, const float* __restrict__ spn,
                       const float* __restrict__ spc, float* __restrict__ out) {
    __shared__ __attribute__((aligned(16))) ushort smem[18208];   // 36416 B
    ushort* lI   = smem;                        // 17408 ush
    float*  sArr = (float*)(smem + 17408);      // 272 f32 (stride 68)
    float*  pnAr = (float*)(smem + 17952);      // 128 f32

    const int tid = threadIdx.x;
    const int n0  = blockIdx.x * 128;           // 2 image rows, same image
    const int b   = n0 >> 12;
    const int y0  = (n0 >> 6) & 63;
    const float* inb = in + b * 262144;

    const int w     = tid >> 6, lane = tid & 63;
    const int fq    = w & 3, mhalf = w >> 2;
    const int quad  = lane >> 4, l16 = lane & 15;
    const int fq2   = fq * 2;

    // B-fragment base (uint4 units): slab*1024 + mat*512 + (fq2+nt)*64 + lane
    const uint4* bp = (const uint4*)wsB + fq2 * 64 + lane;

    // ---- stage image tile once (pn partial fused): 4 rows x 68 px x 8 chunks
    for (int g = tid; g < 2176; g += 512) {
        int row4 = g / 544;                     // 544 = 68*8
        int rem  = g - row4 * 544;
        int px = rem >> 3, c = rem & 7;
        int y = y0 + row4 - 1, x = px - 1;
        float4 v0 = make_float4(0.f, 0.f, 0.f, 0.f), v1 = v0;
        if (y >= 0 && y < 64 && x >= 0 && x < 64) {
            const float* sp = inb + y * 4096 + x * 64 + c * 8;
            v0 = *(const float4*)sp;
            v1 = *(const float4*)(sp + 4);
        }
        uint4 o = { pk(v0.x, v0.y), pk(v0.z, v0.w), pk(v1.x, v1.y), pk(v1.z, v1.w) };
        *(uint4*)&lI[(row4 * 68 + px) * 64 + ((c ^ (px & 7)) << 3)] = o;
        // pixel sqnorm: 8 lanes (c=0..7) of this pixel reduce in-register
        float s8 = v0.x*v0.x + v0.y*v0.y + v0.z*v0.z + v0.w*v0.w
                 + v1.x*v1.x + v1.y*v1.y + v1.z*v1.z + v1.w*v1.w;
        s8 += __shfl_xor(s8, 1, 64);
        s8 += __shfl_xor(s8, 2, 64);
        s8 += __shfl_xor(s8, 4, 64);
        if ((g & 7) == 0) sArr[row4 * 68 + px] = s8;
    }
    __syncthreads();    // lI + sArr visible to all waves

    // ---- pn[m] = 3x3 box sum
    if (tid < 128) {
        int yr = tid >> 6, x = tid & 63;
        float a = 0.f;
        #pragma unroll
        for (int dr = 0; dr < 3; ++dr)
            #pragma unroll
            for (int dc = 0; dc < 3; ++dc)
                a += sArr[(yr + dr) * 68 + x + dc];
        pnAr[tid] = a;
    }
    __syncthreads();    // pnAr visible (loop below is barrier-free)

    f32x4 accW[4][2], accC[4][2];
    #pragma unroll
    for (int mt = 0; mt < 4; ++mt)
        #pragma unroll
        for (int nt = 0; nt < 2; ++nt) {
            accW[mt][nt] = (f32x4){0.f, 0.f, 0.f, 0.f};
            accC[mt][nt] = (f32x4){0.f, 0.f, 0.f, 0.f};
        }

    // ---- 18-slab K-loop: NO barriers, B loaded per-slab from L2 (latency
    //      covered across 5 waves/SIMD; no prefetch regs)
    #pragma unroll 1
    for (int t18 = 0; t18 < 18; ++t18) {
        const int kc = t18 >> 1, ks = t18 & 1;
        const int ki = (kc >= 6) ? 2 : (kc >= 3) ? 1 : 0;
        const int kj = kc - 3 * ki;

        const uint4* np = bp + t18 * 1024;
        uint4 u0 = np[0],   u1 = np[64];
        uint4 u2 = np[512], u3 = np[576];

        bf16x8 bw[2], bc[2];
        bw[0] = __builtin_bit_cast(bf16x8, u0);
        bw[1] = __builtin_bit_cast(bf16x8, u1);
        bc[0] = __builtin_bit_cast(bf16x8, u2);
        bc[1] = __builtin_bit_cast(bf16x8, u3);

        const int swk = (l16 + kj) & 7;
        const int rb0 = (mhalf + ki) * 68 + l16 + kj;
        const int sw  = ((ks * 4 + quad) ^ swk) << 3;
        #pragma unroll
        for (int mt = 0; mt < 4; ++mt) {
            bf16x8 a = *(const bf16x8*)&lI[(rb0 + mt * 16) * 64 + sw];
            #pragma unroll
            for (int nt = 0; nt < 2; ++nt) {
                accW[mt][nt] = __builtin_amdgcn_mfma_f32_16x16x32_bf16(a, bw[nt], accW[mt][nt], 0, 0, 0);
                accC[mt][nt] = __builtin_amdgcn_mfma_f32_16x16x32_bf16(a, bc[nt], accC[mt][nt], 0, 0, 0);
            }
        }
    }

    // ---- epilogue: reduce gamma stats per-wave; C/D col=lane&15, row=quad*4+reg
    float sp = 0.f, sc = 0.f;
    #pragma unroll
    for (int q = 0; q < 8; ++q) {
        sp += spn[q * 64 + lane];
        sc += spc[q * 64 + lane];
    }
    #pragma unroll
    for (int off = 32; off >= 1; off >>= 1) {
        sp += __shfl_xor(sp, off, 64);
        sc += __shfl_xor(sc, off, 64);
    }
    float Sd = 128.f * sp + 131072.f * accum[0] - 2.f * sc;
    float g  = 0.5f * 16777216.f / Sd;
    float bv[2], cv[2];
    #pragma unroll
    for (int nt = 0; nt < 2; ++nt) {
        int gf = fq * 32 + nt * 16 + l16;
        bv[nt] = bias[gf];
        cv[nt] = cn[gf];
    }
    #pragma unroll
    for (int mt = 0; mt < 4; ++mt) {
        int rloc = mhalf * 64 + mt * 16 + quad * 4;
        float pv[4];
        #pragma unroll
        for (int r = 0; r < 4; ++r) pv[r] = pnAr[rloc + r];
        int gm = n0 + rloc;
        #pragma unroll
        for (int nt = 0; nt < 2; ++nt) {
            int gf = fq * 32 + nt * 16 + l16;
            #pragma unroll
            for (int r = 0; r < 4; ++r) {
                float d = pv[r] + cv[nt] - 2.f * accC[mt][nt][r];
                out[(gm + r) * F_ + gf] = accW[mt][nt][r] + bv[nt] + __expf(-g * d);
            }
        }
    }
}

extern "C" void kernel_launch(void* const* d_in, const int* in_sizes, int n_in,
                              void* d_out, int out_size, void* d_ws, size_t ws_size,
                              hipStream_t stream) {
    const float* in   = (const float*)d_in[0];   // [32,64,64,64]
    const float* wgt  = (const float*)d_in[1];   // [3,3,64,128]
    const float* bias = (const float*)d_in[2];   // [128]
    const float* ctrl = (const float*)d_in[3];   // [3,3,64,128]
    float* out = (float*)d_out;

    // ws: wsB @0 (294912 B) | cn @294912 (512 B) | accum @295424 (64 B)
    //     | tab @295488 (2304 B) | spn @297792 (2048 B) | spc @299840 (2048 B)
    char* ws = (char*)d_ws;
    ushort* wsB   = (ushort*)(ws + 0);
    float*  cn    = (float*) (ws + 294912);
    float*  accum = (float*) (ws + 295424);
    float*  tab   = (float*) (ws + 295488);
    float*  spn   = (float*) (ws + 297792);
    float*  spc   = (float*) (ws + 299840);

    k_prep  <<<290,        256, 0, stream>>>(wgt, ctrl, wsB, cn, accum, tab);
    k_gamma <<<NPIX / 256, 256, 0, stream>>>(in, tab, spn, spc);
    k_main  <<<NPIX / 128, 512, 0, stream>>>(in, wsB, bias, cn, accum, spn, spc, out);
}

// Round 14
// 141.900 us; speedup vs baseline: 1.0578x; 1.0578x over previous
//
#include <hip/hip_runtime.h>

// KANConv2D: out[b,h,w,f] = conv3x3(x,K)[.,f] + exp(-gamma * d[.,f]) + bias[f]
// d = ||patch||^2 + ||c_f||^2 - 2*patch.c_f ; gamma = (N*F)/(2*sum(d))
//
// v21 = v13 RESTORED VERBATIM (proven best: 142.5 us total, k_main 48.4).
// 13-round search summary (why this shape is the plateau):
//  - occupancy: acc = 64 AGPR (unified file) + ~50 VGPR => 4 waves/SIMD hard
//    cap. (512,6)/(512,5) spill (v12/v20); 4-wave blocks null (v15).
//  - sync: barrier-free loop beats syncthreads-dbuf, counted-vmcnt, raw
//    barriers (v8/v10/v11 all >= it).
//  - B operand: L2-direct beats all LDS stagings (v13 > v8..v11).
//  - MFMA shape: 32x32x16 -> 2.36M bank conflicts (v18). 16x16x32 is the
//    conflict-free shape for this swizzled tile.
//  - k_gamma/prep reshapes: null on total (v9/v15/v17/v19).
//  - imgbf precompute: k_main -4us but producer +15us (v16).

#define B_ 32
#define H_ 64
#define W_ 64
#define C_ 64
#define F_ 128
#define P_ 576
#define NPIX (B_*H_*W_)          // 131072
#define NF   (NPIX*F_)           // 16777216

typedef __bf16  bf16x8 __attribute__((ext_vector_type(8)));
typedef float   f32x4  __attribute__((ext_vector_type(4)));

union BFU { __bf16 h; ushort s; };
union PKU { __bf16 h[2]; uint u; };

__device__ __forceinline__ ushort f2bf(float f) { BFU q; q.h = (__bf16)f; return q.s; }
__device__ __forceinline__ uint pk(float a, float b) {
    PKU q; q.h[0] = (__bf16)a; q.h[1] = (__bf16)b; return q.u;
}

// ---------------- P: wsB slab pack | cn,Scn | chat tab ----------
// slab s = kc*2+ks (18 slabs x 8192 ushorts). within slab:
//   off = mat*4096 + ntg*512 + (quad*16+l16)*8 + j
//   where p = kc*64 + ks*32 + quad*8 + j, f = ntg*16 + l16.
__global__ void k_prep(const float* __restrict__ wgt, const float* __restrict__ ctrl,
                       ushort* __restrict__ wsB, float* __restrict__ cn,
                       float* __restrict__ accum, float* __restrict__ tab) {
    __shared__ __attribute__((aligned(16))) float sh[1024];
    const int t = threadIdx.x;

    if (blockIdx.x < 288) {
        int e = blockIdx.x * 256 + t;             // < 73728
        int p = e >> 7, f = e & 127;
        int kc = p >> 6, r = p & 63;
        int ks = r >> 5, quad = (r >> 3) & 3, j = r & 7;
        int ntg = f >> 4, l16 = f & 15;
        int off0 = (kc * 2 + ks) * 8192 + ntg * 512 + (quad * 16 + l16) * 8 + j;
        wsB[off0]        = f2bf(wgt[e]);    // mat 0 (kernel)
        wsB[off0 + 4096] = f2bf(ctrl[e]);   // mat 1 (control)
        return;
    }
    if (blockIdx.x == 288) {
        // cn[f] + Scn. thread = (pc 0..7, col 0..31).
        int col = t & 31, pc8 = t >> 5;
        f32x4 a = {0.f, 0.f, 0.f, 0.f};
        const float* base = ctrl + col * 4;
        #pragma unroll 4
        for (int p = pc8 * 72; p < pc8 * 72 + 72; ++p) {
            f32x4 v = *(const f32x4*)(base + p * F_);
            a += v * v;
        }
        f32x4* sh4 = (f32x4*)sh;
        sh4[t] = a;
        __syncthreads();
        f32x4 s = {0.f, 0.f, 0.f, 0.f};
        if (t < 32) {
            #pragma unroll
            for (int q = 0; q < 8; ++q) s += sh4[q * 32 + t];
            *(f32x4*)(cn + t * 4) = s;
        }
        float tot = s.x + s.y + s.z + s.w;   // 0 for t>=32
        if (t < 64) {
            #pragma unroll
            for (int off = 32; off >= 1; off >>= 1) tot += __shfl_down(tot, off, 64);
            if (t == 0) accum[0] = tot;      // Scn
        }
        return;
    }

    // block 289: chat[ki][kj][c] = Sum_f ctrl[ki,kj,c,f]; 9 border variants
    for (int e = t; e < 576; e += 256) {
        const f32x4* row = (const f32x4*)(ctrl + e * F_);
        f32x4 a = {0.f, 0.f, 0.f, 0.f};
        #pragma unroll 8
        for (int q = 0; q < 32; ++q) a += row[q];
        sh[e] = a.x + a.y + a.z + a.w;
    }
    __syncthreads();
    for (int idx = t; idx < 576; idx += 256) {
        int q = idx >> 6, c = idx & 63;       // q = ry*3+rx
        int ry = q / 3, rx = q - 3 * ry;
        int my = (ry == 0) ? 3 : (ry == 2) ? 6 : 7;   // valid-ki bitmask
        int mx = (rx == 0) ? 3 : (rx == 2) ? 6 : 7;
        float s = 0.f;
        #pragma unroll
        for (int ki = 0; ki < 3; ++ki)
            #pragma unroll
            for (int kj = 0; kj < 3; ++kj)
                if ((my >> ki & 1) && (mx >> kj & 1))
                    s += sh[(ki * 3 + kj) * 64 + c];
        tab[idx] = s;
    }
}

// ---------------- G: global stats for gamma (one coalesced input pass) ----------
__launch_bounds__(256)
__global__ void k_gamma(const float* __restrict__ in, const float* __restrict__ tab,
                        float* __restrict__ spn, float* __restrict__ spc) {
    __shared__ float shs[4], shp[4];
    const int t = threadIdx.x, seg = t & 15, grp = t >> 4;
    float s = 0.f, pc = 0.f;
    #pragma unroll 4
    for (int it = 0; it < 16; ++it) {
        int pix = blockIdx.x * 256 + it * 16 + grp;
        int y = (pix >> 6) & 63, x = pix & 63;
        float4 v = *((const float4*)(in + pix * 64) + seg);
        int ry = (y == 0) ? 0 : (y == 63) ? 2 : 1;
        int rx = (x == 0) ? 0 : (x == 63) ? 2 : 1;
        float4 tv = *((const float4*)(tab + (ry * 3 + rx) * 64) + seg);
        float wq = (float)((3 - (y == 0) - (y == 63)) * (3 - (x == 0) - (x == 63)));
        s  += wq * (v.x*v.x + v.y*v.y + v.z*v.z + v.w*v.w);
        pc += v.x*tv.x + v.y*tv.y + v.z*tv.z + v.w*tv.w;
    }
    #pragma unroll
    for (int off = 32; off >= 1; off >>= 1) {
        s  += __shfl_down(s,  off, 64);
        pc += __shfl_down(pc, off, 64);
    }
    if ((t & 63) == 0) { shs[t >> 6] = s; shp[t >> 6] = pc; }
    __syncthreads();
    if (t == 0)  spn[blockIdx.x] = shs[0] + shs[1] + shs[2] + shs[3];
    if (t == 64) spc[blockIdx.x] = shp[0] + shp[1] + shp[2] + shp[3];
}

// ---------------- D: fused dual implicit GEMM, B from L2, barrier-free loop ----
// 512 threads = 8 waves: w = mhalf*4 + fq. Each wave: 64M x 32F, BOTH mats.
// LDS: lI [4][68][64] bf16 (XOR-swizzled) | sArr [4][68] f32 | pnAr [128] f32.
__launch_bounds__(512, 4)
__global__ void k_main(const float* __restrict__ in, const ushort* __restrict__ wsB,
                       const float* __restrict__ bias, const float* __restrict__ cn,
                       const float* __restrict__ accum, const float* __restrict__ spn,
                       const float* __restrict__ spc, float* __restrict__ out) {
    __shared__ __attribute__((aligned(16))) ushort smem[18208];   // 36416 B
    ushort* lI   = smem;                        // 17408 ush
    float*  sArr = (float*)(smem + 17408);      // 272 f32 (stride 68)
    float*  pnAr = (float*)(smem + 17952);      // 128 f32

    const int tid = threadIdx.x;
    const int n0  = blockIdx.x * 128;           // 2 image rows, same image
    const int b   = n0 >> 12;
    const int y0  = (n0 >> 6) & 63;
    const float* inb = in + b * 262144;

    const int w     = tid >> 6, lane = tid & 63;
    const int fq    = w & 3, mhalf = w >> 2;
    const int quad  = lane >> 4, l16 = lane & 15;
    const int fq2   = fq * 2;

    // B-fragment base (uint4 units): slab*1024 + mat*512 + (fq2+nt)*64 + lane
    const uint4* bp = (const uint4*)wsB + fq2 * 64 + lane;

    // ---- preload slab-0 fragments (fly under the staging loop)
    uint4 cw0 = bp[0],   cw1 = bp[64];
    uint4 cc0 = bp[512], cc1 = bp[576];

    // ---- stage image tile once (pn partial fused): 4 rows x 68 px x 8 chunks
    for (int g = tid; g < 2176; g += 512) {
        int row4 = g / 544;                     // 544 = 68*8
        int rem  = g - row4 * 544;
        int px = rem >> 3, c = rem & 7;
        int y = y0 + row4 - 1, x = px - 1;
        float4 v0 = make_float4(0.f, 0.f, 0.f, 0.f), v1 = v0;
        if (y >= 0 && y < 64 && x >= 0 && x < 64) {
            const float* sp = inb + y * 4096 + x * 64 + c * 8;
            v0 = *(const float4*)sp;
            v1 = *(const float4*)(sp + 4);
        }
        uint4 o = { pk(v0.x, v0.y), pk(v0.z, v0.w), pk(v1.x, v1.y), pk(v1.z, v1.w) };
        *(uint4*)&lI[(row4 * 68 + px) * 64 + ((c ^ (px & 7)) << 3)] = o;
        // pixel sqnorm: 8 lanes (c=0..7) of this pixel reduce in-register
        float s8 = v0.x*v0.x + v0.y*v0.y + v0.z*v0.z + v0.w*v0.w
                 + v1.x*v1.x + v1.y*v1.y + v1.z*v1.z + v1.w*v1.w;
        s8 += __shfl_xor(s8, 1, 64);
        s8 += __shfl_xor(s8, 2, 64);
        s8 += __shfl_xor(s8, 4, 64);
        if ((g & 7) == 0) sArr[row4 * 68 + px] = s8;
    }
    __syncthreads();    // lI + sArr visible to all waves

    // ---- pn[m] = 3x3 box sum
    if (tid < 128) {
        int yr = tid >> 6, x = tid & 63;
        float a = 0.f;
        #pragma unroll
        for (int dr = 0; dr < 3; ++dr)
            #pragma unroll
            for (int dc = 0; dc < 3; ++dc)
                a += sArr[(yr + dr) * 68 + x + dc];
        pnAr[tid] = a;
    }
    __syncthreads();    // pnAr visible (loop below is barrier-free)

    f32x4 accW[4][2], accC[4][2];
    #pragma unroll
    for (int mt = 0; mt < 4; ++mt)
        #pragma unroll
        for (int nt = 0; nt < 2; ++nt) {
            accW[mt][nt] = (f32x4){0.f, 0.f, 0.f, 0.f};
            accC[mt][nt] = (f32x4){0.f, 0.f, 0.f, 0.f};
        }

    // ---- 18-slab K-loop: NO barriers, B from L2, depth-1 reg prefetch
    #pragma unroll 1
    for (int t18 = 0; t18 < 18; ++t18) {
        const int kc = t18 >> 1, ks = t18 & 1;
        const int ki = (kc >= 6) ? 2 : (kc >= 3) ? 1 : 0;
        const int kj = kc - 3 * ki;

        uint4 nw0, nw1, nc0, nc1;
        if (t18 < 17) {
            const uint4* np = bp + (t18 + 1) * 1024;
            nw0 = np[0];   nw1 = np[64];
            nc0 = np[512]; nc1 = np[576];
        }

        bf16x8 bw[2], bc[2];
        bw[0] = __builtin_bit_cast(bf16x8, cw0);
        bw[1] = __builtin_bit_cast(bf16x8, cw1);
        bc[0] = __builtin_bit_cast(bf16x8, cc0);
        bc[1] = __builtin_bit_cast(bf16x8, cc1);

        const int swk = (l16 + kj) & 7;
        const int rb0 = (mhalf + ki) * 68 + l16 + kj;
        const int sw  = ((ks * 4 + quad) ^ swk) << 3;
        #pragma unroll
        for (int mt = 0; mt < 4; ++mt) {
            bf16x8 a = *(const bf16x8*)&lI[(rb0 + mt * 16) * 64 + sw];
            #pragma unroll
            for (int nt = 0; nt < 2; ++nt) {
                accW[mt][nt] = __builtin_amdgcn_mfma_f32_16x16x32_bf16(a, bw[nt], accW[mt][nt], 0, 0, 0);
                accC[mt][nt] = __builtin_amdgcn_mfma_f32_16x16x32_bf16(a, bc[nt], accC[mt][nt], 0, 0, 0);
            }
        }
        cw0 = nw0; cw1 = nw1; cc0 = nc0; cc1 = nc1;
    }

    // ---- epilogue: reduce gamma stats per-wave; C/D col=lane&15, row=quad*4+reg
    float sp = 0.f, sc = 0.f;
    #pragma unroll
    for (int q = 0; q < 8; ++q) {
        sp += spn[q * 64 + lane];
        sc += spc[q * 64 + lane];
    }
    #pragma unroll
    for (int off = 32; off >= 1; off >>= 1) {
        sp += __shfl_xor(sp, off, 64);
        sc += __shfl_xor(sc, off, 64);
    }
    float Sd = 128.f * sp + 131072.f * accum[0] - 2.f * sc;
    float g  = 0.5f * 16777216.f / Sd;
    float bv[2], cv[2];
    #pragma unroll
    for (int nt = 0; nt < 2; ++nt) {
        int gf = fq * 32 + nt * 16 + l16;
        bv[nt] = bias[gf];
        cv[nt] = cn[gf];
    }
    #pragma unroll
    for (int mt = 0; mt < 4; ++mt) {
        int rloc = mhalf * 64 + mt * 16 + quad * 4;
        float pv[4];
        #pragma unroll
        for (int r = 0; r < 4; ++r) pv[r] = pnAr[rloc + r];
        int gm = n0 + rloc;
        #pragma unroll
        for (int nt = 0; nt < 2; ++nt) {
            int gf = fq * 32 + nt * 16 + l16;
            #pragma unroll
            for (int r = 0; r < 4; ++r) {
                float d = pv[r] + cv[nt] - 2.f * accC[mt][nt][r];
                out[(gm + r) * F_ + gf] = accW[mt][nt][r] + bv[nt] + __expf(-g * d);
            }
        }
    }
}

extern "C" void kernel_launch(void* const* d_in, const int* in_sizes, int n_in,
                              void* d_out, int out_size, void* d_ws, size_t ws_size,
                              hipStream_t stream) {
    const float* in   = (const float*)d_in[0];   // [32,64,64,64]
    const float* wgt  = (const float*)d_in[1];   // [3,3,64,128]
    const float* bias = (const float*)d_in[2];   // [128]
    const float* ctrl = (const float*)d_in[3];   // [3,3,64,128]
    float* out = (float*)d_out;

    // ws: wsB @0 (294912 B) | cn @294912 (512 B) | accum @295424 (64 B)
    //     | tab @295488 (2304 B) | spn @297792 (2048 B) | spc @299840 (2048 B)
    char* ws = (char*)d_ws;
    ushort* wsB   = (ushort*)(ws + 0);
    float*  cn    = (float*) (ws + 294912);
    float*  accum = (float*) (ws + 295424);
    float*  tab   = (float*) (ws + 295488);
    float*  spn   = (float*) (ws + 297792);
    float*  spc   = (float*) (ws + 299840);

    k_prep  <<<290,        256, 0, stream>>>(wgt, ctrl, wsB, cn, accum, tab);
    k_gamma <<<NPIX / 256, 256, 0, stream>>>(in, tab, spn, spc);
    k_main  <<<NPIX / 128, 512, 0, stream>>>(in, wsB, bias, cn, accum, spn, spc, out);
}